// Round 3
// baseline (397.793 us; speedup 1.0000x reference)
//
#include <hip/hip_runtime.h>
#include <hip/hip_bf16.h>
#include <math.h>

// Problem constants
// B=32, C=64 (Cin==Cout), N=8192, modes F=32, L=20 segments, M=8 Chebyshev
#define NN    8192
#define NROWS 2048      // B*C
#define FF    32
#define LM    160       // L*M

// Workspace layout (float offsets)
// TRIG4 layout: [k4][f][4] : ws[TRIG + (k4*64+f)*4 + j] =
//   f<32 ? cos(2pi f (4k4+j)/N) : sin(2pi (f-32)(4k4+j)/N)
static constexpr int TRIG  = 0;         // 2048*64*4 = 524288 floats
static constexpr int W1RT  = 524288;    // [f][i][o] 32*64*64
static constexpr int W1IT  = 655360;
static constexpr int GWT   = 786432;    // [i][o] 64*64
static constexpr int AR_   = 790528;    // [160][32]
static constexpr int AI_   = 795648;
static constexpr int WL_   = 800768;    // [160]
static constexpr int WR_   = 800928;
static constexpr int IL_   = 801088;    // int [160]
static constexpr int IR_   = 801248;
static constexpr int XR_   = 801408;    // [2048][32]
static constexpr int XI_   = 866944;
static constexpr int GN_   = 932480;    // [2048][32]
static constexpr int ARAI  = 998016;    // [2048][64]: [0..31]=cos coeff, [32..63]=sin coeff
// total = 1129088 floats = 4.31 MB

#define PI_D 3.14159265358979323846

// ---------------- A1: trig table, TRIG4 layout ----------------
__global__ __launch_bounds__(256) void k_trig(float* __restrict__ ws) {
  int idx = blockIdx.x * 256 + threadIdx.x;   // 0..524287
  // element offset == idx: idx = (k4*64+f)*4 + j
  int k4 = idx >> 8, f = (idx >> 2) & 63, j = idx & 3;
  int n = 4 * k4 + j;
  int fr = f & 31;
  int p = (fr * n) & (NN - 1);
  float ang = (float)p * (float)(2.0 * PI_D / (double)NN);
  float s, c;
  sincosf(ang, &s, &c);
  ws[TRIG + idx] = (f < 32) ? c : s;
}

// ---------------- A2: CFT constant tables (double precision, parallel) ----------------
__global__ __launch_bounds__(256) void k_cft_tables(float* __restrict__ ws) {
  int tid = blockIdx.x * 256 + threadIdx.x;
  if (tid >= LM * FF) return;
  int j = tid >> 5, f = tid & 31;
  int l = j >> 3, m = j & 7;      // m doubles as Chebyshev order k
  double cheb[8];
  #pragma unroll
  for (int mm = 0; mm < 8; ++mm)
    cheb[mm] = -cos((2.0 * mm + 1.0) * PI_D / 16.0);

  // combined quadrature weights Ar/Ai for (j,f)
  double Wr = 0.0, Wi = 0.0;
  #pragma unroll
  for (int mm = 0; mm < 8; ++mm) {
    double T = cos((double)m * acos(cheb[mm]));
    double ang = cheb[mm] * (double)f * (PI_D * 0.05);
    Wr += T * cos(ang);
    Wi += T * (-sin(ang));
  }
  Wr *= 0.025; Wi *= 0.025;
  double phi = 2.0 * PI_D * ((double)l * 0.05) * (double)f;
  double cs = cos(phi), sn = sin(phi);
  ws[AR_ + j * FF + f] = (float)(Wr * cs + Wi * sn);
  ws[AI_ + j * FF + f] = (float)(-Wr * sn + Wi * cs);

  if (f == 0) {
    // interpolation index/weights at t_seg(l, m)
    double v = (double)l * 0.05 + 0.025 * (cheb[m] + 1.0);
    int r = (int)(v * 8191.0);
    while ((double)r / 8191.0 < v) ++r;
    while (r > 0 && (double)(r - 1) / 8191.0 >= v) --r;
    if (r > 8191) r = 8191;
    int le = r - 1; if (le < 0) le = 0;
    double tl = (double)le / 8191.0, tr = (double)r / 8191.0;
    double den = (tr - tl == 0.0) ? 1.0 : (tr - tl);
    double wr = (v - tl) / den;
    ws[WL_ + j] = (float)(1.0 - wr);
    ws[WR_ + j] = (float)wr;
    ((int*)ws)[IL_ + j] = le;
    ((int*)ws)[IR_ + j] = r;
  }
}

// ---------------- A3: transposes ----------------
__global__ __launch_bounds__(256) void k_transpose(const float* __restrict__ w1r,
                                                   const float* __restrict__ w1i,
                                                   const float* __restrict__ gw,
                                                   float* __restrict__ ws) {
  int idx = blockIdx.x * 256 + threadIdx.x;   // 0..131071
  if (idx >= 32 * 64 * 64) return;
  int o = idx & 63, i = (idx >> 6) & 63, f = idx >> 12;   // f in 0..31
  ws[W1RT + (f * 64 + i) * 64 + o] = w1r[(i * 64 + o) * FF + f];
  ws[W1IT + (f * 64 + i) * 64 + o] = w1i[(i * 64 + o) * FF + f];
  if (idx < 4096) {
    ws[GWT + idx] = gw[(idx & 63) * 64 + (idx >> 6)];
  }
}

// ---------------- B1: forward truncated DFT as split-K GEMM ----------------
// grid = 32 row-tiles x 32 K-chunks. Block = 256 thr = 4 waves.
// Wave w: rows rt*64 + w*16 .. +15, lane = f (0..63: 0-31 cos, 32-63 sin).
// x values are wave-uniform -> scalar loads (readfirstlane-forced).
// Partials into `part` (= d_out scratch): part[kc][row][64].
__global__ __launch_bounds__(256) void k_fwd_gemm(const float* __restrict__ x,
                                                  const float* __restrict__ ws,
                                                  float* __restrict__ part) {
  const int rt = blockIdx.x >> 5, kc = blockIdx.x & 31;
  const int w = threadIdx.x >> 6, lane = threadIdx.x & 63;
  const int rbase = __builtin_amdgcn_readfirstlane(rt * 64 + w * 16);
  const float* __restrict__ xw = x + (size_t)rbase * NN;
  const float4* __restrict__ tg4 = (const float4*)(ws + TRIG);

  float acc[16];
  #pragma unroll
  for (int r = 0; r < 16; ++r) acc[r] = 0.f;

  const int k40 = kc * 64;                     // 64 k4-iters = 256 k per chunk
  for (int it = 0; it < 64; ++it) {
    const int k4 = k40 + it;
    float4 tg = tg4[(size_t)k4 * 64 + lane];   // coalesced 1KB/wave
    const float* __restrict__ xk = xw + (size_t)k4 * 4;
    #pragma unroll
    for (int r = 0; r < 16; ++r) {
      const float4 xv = *(const float4*)(xk + (size_t)r * NN);   // uniform -> s_load_dwordx4
      acc[r] = fmaf(xv.w, tg.w, fmaf(xv.z, tg.z, fmaf(xv.y, tg.y, fmaf(xv.x, tg.x, acc[r]))));
    }
  }
  float* __restrict__ pp = part + ((size_t)kc * NROWS + rbase) * 64 + lane;
  #pragma unroll
  for (int r = 0; r < 16; ++r)
    pp[(size_t)r * 64] = acc[r];
}

// ---------------- B2: split-K reduce -> XR_/XI_ ----------------
__global__ __launch_bounds__(256) void k_fred(const float* __restrict__ part,
                                              float* __restrict__ ws) {
  int idx = blockIdx.x * 256 + threadIdx.x;   // 0..131071
  int row = idx >> 6, f = idx & 63;
  float s = 0.f;
  #pragma unroll
  for (int kc = 0; kc < 32; ++kc)
    s += part[((size_t)kc * NROWS + row) * 64 + f];
  if (f < 32) ws[XR_ + row * FF + f] = s;
  else        ws[XI_ + row * FF + (f - 32)] = -s;   // rfft imag = -sum x sin
}

// ---------------- B3: CFT magnitude + LayerNorm (per row) ----------------
__global__ __launch_bounds__(256) void k_cft(const float* __restrict__ x,
                                             const float* __restrict__ gamma,
                                             const float* __restrict__ beta,
                                             float* __restrict__ ws) {
  const int sub = threadIdx.x >> 6, li = threadIdx.x & 63;
  const int row = blockIdx.x * 4 + sub;
  const float* __restrict__ xr = x + (size_t)row * NN;
  __shared__ float seg[4][LM];
  #pragma unroll
  for (int g = 0; g < 3; ++g) {
    int j = li + 64 * g;
    if (j < LM) {
      int il = ((const int*)ws)[IL_ + j];
      int ir = ((const int*)ws)[IR_ + j];
      seg[sub][j] = ws[WL_ + j] * xr[il] + ws[WR_ + j] * xr[ir];
    }
  }
  __syncthreads();
  if (li < FF) {
    float re = 0.f, im = 0.f;
    #pragma unroll 8
    for (int j = 0; j < LM; ++j) {
      float sv = seg[sub][j];
      re = fmaf(sv, ws[AR_ + j * FF + li], re);
      im = fmaf(sv, ws[AI_ + j * FF + li], im);
    }
    float mag = sqrtf(re * re + im * im);
    float mu = mag;
    mu += __shfl_xor(mu, 1);  mu += __shfl_xor(mu, 2);  mu += __shfl_xor(mu, 4);
    mu += __shfl_xor(mu, 8);  mu += __shfl_xor(mu, 16);
    mu *= (1.0f / 32.0f);
    float d = mag - mu;
    float vv = d * d;
    vv += __shfl_xor(vv, 1);  vv += __shfl_xor(vv, 2);  vv += __shfl_xor(vv, 4);
    vv += __shfl_xor(vv, 8);  vv += __shfl_xor(vv, 16);
    vv *= (1.0f / 32.0f);
    float g = d / sqrtf(vv + 1e-5f) * gamma[li] + beta[li];
    ws[GN_ + row * FF + li] = g;
  }
}

// ---------------- C: gate (LN -> 1x1 conv -> sigmoid) + complex channel mix ----------------
__global__ __launch_bounds__(64) void k_gate(float* __restrict__ ws) {
  int bidx = blockIdx.x;                 // b*32 + f
  int b = bidx >> 5, f = bidx & 31;
  int o = threadIdx.x;
  __shared__ float gn[64], gr[64], gi[64];
  int rowb = b * 64;
  gn[o] = ws[GN_ + (rowb + o) * FF + f];
  float xre = ws[XR_ + (rowb + o) * FF + f];
  float xim = ws[XI_ + (rowb + o) * FF + f];
  __syncthreads();
  float acc = 0.f;
  #pragma unroll 16
  for (int i = 0; i < 64; ++i)
    acc = fmaf(ws[GWT + i * 64 + o], gn[i], acc);
  float gate = 1.0f / (1.0f + expf(-acc));
  gr[o] = xre * gate;
  gi[o] = xim * gate;
  __syncthreads();
  float Yr = 0.f, Yi = 0.f;
  const float* __restrict__ w1rt = ws + W1RT + f * 4096;
  const float* __restrict__ w1it = ws + W1IT + f * 4096;
  #pragma unroll 8
  for (int i = 0; i < 64; ++i) {
    float a = gr[i], bb2 = gi[i];
    float wr = w1rt[i * 64 + o], wi = w1it[i * 64 + o];
    Yr = fmaf(a, wr, Yr); Yr = fmaf(-bb2, wi, Yr);
    Yi = fmaf(a, wi, Yi); Yi = fmaf(bb2, wr, Yi);
  }
  float* A = ws + ARAI + (size_t)(rowb + o) * 64;
  if (f == 0) {
    A[0]  = Yr * (1.0f / (float)NN);
    A[32] = 0.0f;
  } else {
    A[f]      = Yr * (2.0f / (float)NN);
    A[32 + f] = -Yi * (2.0f / (float)NN);
  }
}

// ---------------- D: inverse (2048x64)@(64x8192) GEMM vs trig table ----------------
__global__ __launch_bounds__(256) void k_inv(const float* __restrict__ ws,
                                             float* __restrict__ out) {
  __shared__ __align__(16) float T_s[64 * 256];   // logical [f][256 cols], 64 KB
  int blk = blockIdx.x;
  int bb = blk >> 5, cc = blk & 31;               // 32 row-tiles x 32 col-tiles(256)
  int t = threadIdx.x;
  int cx = t & 15, ry = t >> 4;

  {
    const int base4 = cc * 64;                    // k4 base of this 256-col tile
    #pragma unroll
    for (int r2 = 0; r2 < 16; ++r2) {
      int q = t + 256 * r2;                       // 0..4095
      int f = q & 63, c4 = q >> 6;                // c4 0..63
      float4 v = *(const float4*)(ws + TRIG + (size_t)((base4 + c4) * 64 + f) * 4);
      *(float4*)(&T_s[f * 256 + c4 * 4]) = v;
    }
  }
  __syncthreads();

  float acc[4][16];
  #pragma unroll
  for (int r = 0; r < 4; ++r)
    #pragma unroll
    for (int k = 0; k < 16; ++k) acc[r][k] = 0.f;

  const float* __restrict__ Ab = ws + ARAI + (size_t)(bb * 64) * 64;
  for (int j0 = 0; j0 < 64; j0 += 4) {
    float4 av[4];
    #pragma unroll
    for (int r = 0; r < 4; ++r)
      av[r] = *(const float4*)(Ab + (ry * 4 + r) * 64 + j0);
    #pragma unroll
    for (int jj = 0; jj < 4; ++jj) {
      int j = j0 + jj;
      const float* Trow = &T_s[j * 256 + cx * 4];
      float4 t0 = *(const float4*)(Trow);
      float4 t1 = *(const float4*)(Trow + 64);
      float4 t2 = *(const float4*)(Trow + 128);
      float4 t3 = *(const float4*)(Trow + 192);
      #pragma unroll
      for (int r = 0; r < 4; ++r) {
        float a = ((const float*)&av[r])[jj];
        acc[r][0]  = fmaf(a, t0.x, acc[r][0]);
        acc[r][1]  = fmaf(a, t0.y, acc[r][1]);
        acc[r][2]  = fmaf(a, t0.z, acc[r][2]);
        acc[r][3]  = fmaf(a, t0.w, acc[r][3]);
        acc[r][4]  = fmaf(a, t1.x, acc[r][4]);
        acc[r][5]  = fmaf(a, t1.y, acc[r][5]);
        acc[r][6]  = fmaf(a, t1.z, acc[r][6]);
        acc[r][7]  = fmaf(a, t1.w, acc[r][7]);
        acc[r][8]  = fmaf(a, t2.x, acc[r][8]);
        acc[r][9]  = fmaf(a, t2.y, acc[r][9]);
        acc[r][10] = fmaf(a, t2.z, acc[r][10]);
        acc[r][11] = fmaf(a, t2.w, acc[r][11]);
        acc[r][12] = fmaf(a, t3.x, acc[r][12]);
        acc[r][13] = fmaf(a, t3.y, acc[r][13]);
        acc[r][14] = fmaf(a, t3.z, acc[r][14]);
        acc[r][15] = fmaf(a, t3.w, acc[r][15]);
      }
    }
  }
  #pragma unroll
  for (int r = 0; r < 4; ++r) {
    int row = bb * 64 + ry * 4 + r;
    float* op = out + (size_t)row * NN + cc * 256;
    #pragma unroll
    for (int q = 0; q < 4; ++q) {
      float4 v = make_float4(acc[r][4*q+0], acc[r][4*q+1], acc[r][4*q+2], acc[r][4*q+3]);
      *(float4*)(op + q * 64 + cx * 4) = v;
    }
  }
}

extern "C" void kernel_launch(void* const* d_in, const int* in_sizes, int n_in,
                              void* d_out, int out_size, void* d_ws, size_t ws_size,
                              hipStream_t stream) {
  const float* x     = (const float*)d_in[0];   // (32,64,8192)
  const float* w1r   = (const float*)d_in[1];   // (64,64,32)
  const float* w1i   = (const float*)d_in[2];   // (64,64,32)
  const float* gw    = (const float*)d_in[3];   // (64,64)
  const float* gamma = (const float*)d_in[4];   // (32,)
  const float* beta  = (const float*)d_in[5];   // (32,)
  float* out = (float*)d_out;                   // (32,64,8192)
  float* ws = (float*)d_ws;
  // split-K partials live in d_out (16 MB of its 64 MB) — fully overwritten by k_inv later
  float* part = (float*)d_out;

  hipLaunchKernelGGL(k_trig,       dim3(2048), dim3(256), 0, stream, ws);
  hipLaunchKernelGGL(k_cft_tables, dim3(20),   dim3(256), 0, stream, ws);
  hipLaunchKernelGGL(k_transpose,  dim3(512),  dim3(256), 0, stream, w1r, w1i, gw, ws);
  hipLaunchKernelGGL(k_fwd_gemm,   dim3(1024), dim3(256), 0, stream, x, ws, part);
  hipLaunchKernelGGL(k_fred,       dim3(512),  dim3(256), 0, stream, part, ws);
  hipLaunchKernelGGL(k_cft,        dim3(512),  dim3(256), 0, stream, x, gamma, beta, ws);
  hipLaunchKernelGGL(k_gate,       dim3(1024), dim3(64),  0, stream, ws);
  hipLaunchKernelGGL(k_inv,        dim3(1024), dim3(256), 0, stream, ws, out);
}

// Round 4
// 213.918 us; speedup vs baseline: 1.8596x; 1.8596x over previous
//
#include <hip/hip_runtime.h>
#include <hip/hip_bf16.h>
#include <math.h>

// Problem constants
// B=32, C=64 (Cin==Cout), N=8192, modes F=32, L=20 segments, M=8 Chebyshev
#define NN    8192
#define NROWS 2048      // B*C
#define FF    32
#define LM    160       // L*M

// Workspace layout (float offsets)
// TRIG4 layout: [k4][f][4] : ws[TRIG + (k4*64+f)*4 + j] =
//   f<32 ? cos(2pi f (4k4+j)/N) : sin(2pi (f-32)(4k4+j)/N)
static constexpr int TRIG  = 0;         // 2048*64*4 = 524288 floats
static constexpr int W1RT  = 524288;    // [f][i][o] 32*64*64
static constexpr int W1IT  = 655360;
static constexpr int GWT   = 786432;    // [i][o] 64*64
static constexpr int AR_   = 790528;    // [160][32]
static constexpr int AI_   = 795648;
static constexpr int WL_   = 800768;    // [160]
static constexpr int WR_   = 800928;
static constexpr int IL_   = 801088;    // int [160]
static constexpr int IR_   = 801248;
static constexpr int XR_   = 801408;    // [2048][32]
static constexpr int XI_   = 866944;
static constexpr int GN_   = 932480;    // [2048][32]
static constexpr int ARAI  = 998016;    // [2048][64]: [0..31]=cos coeff, [32..63]=sin coeff
// total = 1129088 floats = 4.31 MB

#define PI_D 3.14159265358979323846

// ---------------- A1: trig table, TRIG4 layout ----------------
__global__ __launch_bounds__(256) void k_trig(float* __restrict__ ws) {
  int idx = blockIdx.x * 256 + threadIdx.x;   // 0..524287
  int k4 = idx >> 8, f = (idx >> 2) & 63, j = idx & 3;
  int n = 4 * k4 + j;
  int fr = f & 31;
  int p = (fr * n) & (NN - 1);
  float ang = (float)p * (float)(2.0 * PI_D / (double)NN);
  float s, c;
  sincosf(ang, &s, &c);
  ws[TRIG + idx] = (f < 32) ? c : s;
}

// ---------------- A2: CFT constant tables (double precision, parallel) ----------------
__global__ __launch_bounds__(256) void k_cft_tables(float* __restrict__ ws) {
  int tid = blockIdx.x * 256 + threadIdx.x;
  if (tid >= LM * FF) return;
  int j = tid >> 5, f = tid & 31;
  int l = j >> 3, m = j & 7;      // m doubles as Chebyshev order k
  double cheb[8];
  #pragma unroll
  for (int mm = 0; mm < 8; ++mm)
    cheb[mm] = -cos((2.0 * mm + 1.0) * PI_D / 16.0);

  double Wr = 0.0, Wi = 0.0;
  #pragma unroll
  for (int mm = 0; mm < 8; ++mm) {
    double T = cos((double)m * acos(cheb[mm]));
    double ang = cheb[mm] * (double)f * (PI_D * 0.05);
    Wr += T * cos(ang);
    Wi += T * (-sin(ang));
  }
  Wr *= 0.025; Wi *= 0.025;
  double phi = 2.0 * PI_D * ((double)l * 0.05) * (double)f;
  double cs = cos(phi), sn = sin(phi);
  ws[AR_ + j * FF + f] = (float)(Wr * cs + Wi * sn);
  ws[AI_ + j * FF + f] = (float)(-Wr * sn + Wi * cs);

  if (f == 0) {
    double v = (double)l * 0.05 + 0.025 * (cheb[m] + 1.0);
    int r = (int)(v * 8191.0);
    while ((double)r / 8191.0 < v) ++r;
    while (r > 0 && (double)(r - 1) / 8191.0 >= v) --r;
    if (r > 8191) r = 8191;
    int le = r - 1; if (le < 0) le = 0;
    double tl = (double)le / 8191.0, tr = (double)r / 8191.0;
    double den = (tr - tl == 0.0) ? 1.0 : (tr - tl);
    double wr = (v - tl) / den;
    ws[WL_ + j] = (float)(1.0 - wr);
    ws[WR_ + j] = (float)wr;
    ((int*)ws)[IL_ + j] = le;
    ((int*)ws)[IR_ + j] = r;
  }
}

// ---------------- A3: transposes ----------------
__global__ __launch_bounds__(256) void k_transpose(const float* __restrict__ w1r,
                                                   const float* __restrict__ w1i,
                                                   const float* __restrict__ gw,
                                                   float* __restrict__ ws) {
  int idx = blockIdx.x * 256 + threadIdx.x;   // 0..131071
  if (idx >= 32 * 64 * 64) return;
  int o = idx & 63, i = (idx >> 6) & 63, f = idx >> 12;   // f in 0..31
  ws[W1RT + (f * 64 + i) * 64 + o] = w1r[(i * 64 + o) * FF + f];
  ws[W1IT + (f * 64 + i) * 64 + o] = w1i[(i * 64 + o) * FF + f];
  if (idx < 4096) {
    ws[GWT + idx] = gw[(idx & 63) * 64 + (idx >> 6)];
  }
}

// ---------------- B1: forward truncated DFT, split-K GEMM w/ LDS-staged x ----------------
// grid = 32 row-tiles x 32 K-chunks (chunk = 256 k, staged as 2x128k in LDS).
// Block 256 thr = 4 waves; wave w: rows rt*64+w*16..+15, lane = f (0-31 cos, 32-63 sin).
// x from LDS via same-address broadcast ds_read_b128 (free per m136);
// trig via coalesced float4 (L2-resident).  Partials -> part[kc][row][64] in d_out.
__global__ __launch_bounds__(256, 4) void k_fwd_gemm(const float* __restrict__ x,
                                                     const float* __restrict__ ws,
                                                     float* __restrict__ part) {
  __shared__ __align__(16) float xs[64 * 128];   // 32 KB
  const int rt = blockIdx.x >> 5, kc = blockIdx.x & 31;
  const int t = threadIdx.x;
  const int w = t >> 6, lane = t & 63;
  const int rblock = rt * 64;
  const float4* __restrict__ tg4 = (const float4*)(ws + TRIG);

  float acc[16];
  #pragma unroll
  for (int r = 0; r < 16; ++r) acc[r] = 0.f;

  const int c4 = t & 31, r0 = t >> 5;           // staging: 32 float4/row, 8 rows/pass
  for (int st = 0; st < 2; ++st) {
    const int kb = kc * 256 + st * 128;         // k base of this stage
    __syncthreads();                            // protect xs from previous stage's readers
    #pragma unroll
    for (int p = 0; p < 8; ++p) {
      int row = r0 + 8 * p;
      float4 v = *(const float4*)(x + (size_t)(rblock + row) * NN + kb + c4 * 4);
      *(float4*)(&xs[row * 128 + c4 * 4]) = v;
    }
    __syncthreads();
    const int k40 = (kb >> 2);                  // global k4 index base
    for (int it = 0; it < 32; ++it) {
      float4 tg = tg4[(size_t)(k40 + it) * 64 + lane];   // coalesced 1KB/wave
      const float* xw = &xs[(w * 16) * 128 + it * 4];
      #pragma unroll
      for (int r = 0; r < 16; ++r) {
        float4 xv = *(const float4*)(xw + r * 128);      // broadcast b128
        acc[r] = fmaf(xv.w, tg.w, fmaf(xv.z, tg.z, fmaf(xv.y, tg.y, fmaf(xv.x, tg.x, acc[r]))));
      }
    }
  }
  float* __restrict__ pp = part + ((size_t)kc * NROWS + rblock + w * 16) * 64 + lane;
  #pragma unroll
  for (int r = 0; r < 16; ++r)
    pp[(size_t)r * 64] = acc[r];
}

// ---------------- B2: split-K reduce -> XR_/XI_ ----------------
__global__ __launch_bounds__(256) void k_fred(const float* __restrict__ part,
                                              float* __restrict__ ws) {
  int idx = blockIdx.x * 256 + threadIdx.x;   // 0..131071
  int row = idx >> 6, f = idx & 63;
  float s = 0.f;
  #pragma unroll
  for (int kc = 0; kc < 32; ++kc)
    s += part[((size_t)kc * NROWS + row) * 64 + f];
  if (f < 32) ws[XR_ + row * FF + f] = s;
  else        ws[XI_ + row * FF + (f - 32)] = -s;   // rfft imag = -sum x sin
}

// ---------------- B3: CFT magnitude + LayerNorm (per row) ----------------
__global__ __launch_bounds__(256) void k_cft(const float* __restrict__ x,
                                             const float* __restrict__ gamma,
                                             const float* __restrict__ beta,
                                             float* __restrict__ ws) {
  const int sub = threadIdx.x >> 6, li = threadIdx.x & 63;
  const int row = blockIdx.x * 4 + sub;
  const float* __restrict__ xr = x + (size_t)row * NN;
  __shared__ float seg[4][LM];
  #pragma unroll
  for (int g = 0; g < 3; ++g) {
    int j = li + 64 * g;
    if (j < LM) {
      int il = ((const int*)ws)[IL_ + j];
      int ir = ((const int*)ws)[IR_ + j];
      seg[sub][j] = ws[WL_ + j] * xr[il] + ws[WR_ + j] * xr[ir];
    }
  }
  __syncthreads();
  if (li < FF) {
    float re = 0.f, im = 0.f;
    #pragma unroll 8
    for (int j = 0; j < LM; ++j) {
      float sv = seg[sub][j];
      re = fmaf(sv, ws[AR_ + j * FF + li], re);
      im = fmaf(sv, ws[AI_ + j * FF + li], im);
    }
    float mag = sqrtf(re * re + im * im);
    float mu = mag;
    mu += __shfl_xor(mu, 1);  mu += __shfl_xor(mu, 2);  mu += __shfl_xor(mu, 4);
    mu += __shfl_xor(mu, 8);  mu += __shfl_xor(mu, 16);
    mu *= (1.0f / 32.0f);
    float d = mag - mu;
    float vv = d * d;
    vv += __shfl_xor(vv, 1);  vv += __shfl_xor(vv, 2);  vv += __shfl_xor(vv, 4);
    vv += __shfl_xor(vv, 8);  vv += __shfl_xor(vv, 16);
    vv *= (1.0f / 32.0f);
    float g = d / sqrtf(vv + 1e-5f) * gamma[li] + beta[li];
    ws[GN_ + row * FF + li] = g;
  }
}

// ---------------- C: gate (LN -> 1x1 conv -> sigmoid) + complex channel mix ----------------
__global__ __launch_bounds__(64) void k_gate(float* __restrict__ ws) {
  int bidx = blockIdx.x;                 // b*32 + f
  int b = bidx >> 5, f = bidx & 31;
  int o = threadIdx.x;
  __shared__ float gn[64], gr[64], gi[64];
  int rowb = b * 64;
  gn[o] = ws[GN_ + (rowb + o) * FF + f];
  float xre = ws[XR_ + (rowb + o) * FF + f];
  float xim = ws[XI_ + (rowb + o) * FF + f];
  __syncthreads();
  float acc = 0.f;
  #pragma unroll 16
  for (int i = 0; i < 64; ++i)
    acc = fmaf(ws[GWT + i * 64 + o], gn[i], acc);
  float gate = 1.0f / (1.0f + expf(-acc));
  gr[o] = xre * gate;
  gi[o] = xim * gate;
  __syncthreads();
  float Yr = 0.f, Yi = 0.f;
  const float* __restrict__ w1rt = ws + W1RT + f * 4096;
  const float* __restrict__ w1it = ws + W1IT + f * 4096;
  #pragma unroll 8
  for (int i = 0; i < 64; ++i) {
    float a = gr[i], bb2 = gi[i];
    float wr = w1rt[i * 64 + o], wi = w1it[i * 64 + o];
    Yr = fmaf(a, wr, Yr); Yr = fmaf(-bb2, wi, Yr);
    Yi = fmaf(a, wi, Yi); Yi = fmaf(bb2, wr, Yi);
  }
  float* A = ws + ARAI + (size_t)(rowb + o) * 64;
  if (f == 0) {
    A[0]  = Yr * (1.0f / (float)NN);
    A[32] = 0.0f;
  } else {
    A[f]      = Yr * (2.0f / (float)NN);
    A[32 + f] = -Yi * (2.0f / (float)NN);
  }
}

// ---------------- D: inverse (2048x64)@(64x8192) GEMM vs trig table ----------------
__global__ __launch_bounds__(256) void k_inv(const float* __restrict__ ws,
                                             float* __restrict__ out) {
  __shared__ __align__(16) float T_s[64 * 256];   // logical [f][256 cols], 64 KB
  int blk = blockIdx.x;
  int bb = blk >> 5, cc = blk & 31;               // 32 row-tiles x 32 col-tiles(256)
  int t = threadIdx.x;
  int cx = t & 15, ry = t >> 4;

  {
    const int base4 = cc * 64;                    // k4 base of this 256-col tile
    #pragma unroll
    for (int r2 = 0; r2 < 16; ++r2) {
      int q = t + 256 * r2;                       // 0..4095
      int f = q & 63, c4 = q >> 6;                // c4 0..63
      float4 v = *(const float4*)(ws + TRIG + (size_t)((base4 + c4) * 64 + f) * 4);
      *(float4*)(&T_s[f * 256 + c4 * 4]) = v;
    }
  }
  __syncthreads();

  float acc[4][16];
  #pragma unroll
  for (int r = 0; r < 4; ++r)
    #pragma unroll
    for (int k = 0; k < 16; ++k) acc[r][k] = 0.f;

  const float* __restrict__ Ab = ws + ARAI + (size_t)(bb * 64) * 64;
  for (int j0 = 0; j0 < 64; j0 += 4) {
    float4 av[4];
    #pragma unroll
    for (int r = 0; r < 4; ++r)
      av[r] = *(const float4*)(Ab + (ry * 4 + r) * 64 + j0);
    #pragma unroll
    for (int jj = 0; jj < 4; ++jj) {
      int j = j0 + jj;
      const float* Trow = &T_s[j * 256 + cx * 4];
      float4 t0 = *(const float4*)(Trow);
      float4 t1 = *(const float4*)(Trow + 64);
      float4 t2 = *(const float4*)(Trow + 128);
      float4 t3 = *(const float4*)(Trow + 192);
      #pragma unroll
      for (int r = 0; r < 4; ++r) {
        float a = ((const float*)&av[r])[jj];
        acc[r][0]  = fmaf(a, t0.x, acc[r][0]);
        acc[r][1]  = fmaf(a, t0.y, acc[r][1]);
        acc[r][2]  = fmaf(a, t0.z, acc[r][2]);
        acc[r][3]  = fmaf(a, t0.w, acc[r][3]);
        acc[r][4]  = fmaf(a, t1.x, acc[r][4]);
        acc[r][5]  = fmaf(a, t1.y, acc[r][5]);
        acc[r][6]  = fmaf(a, t1.z, acc[r][6]);
        acc[r][7]  = fmaf(a, t1.w, acc[r][7]);
        acc[r][8]  = fmaf(a, t2.x, acc[r][8]);
        acc[r][9]  = fmaf(a, t2.y, acc[r][9]);
        acc[r][10] = fmaf(a, t2.z, acc[r][10]);
        acc[r][11] = fmaf(a, t2.w, acc[r][11]);
        acc[r][12] = fmaf(a, t3.x, acc[r][12]);
        acc[r][13] = fmaf(a, t3.y, acc[r][13]);
        acc[r][14] = fmaf(a, t3.z, acc[r][14]);
        acc[r][15] = fmaf(a, t3.w, acc[r][15]);
      }
    }
  }
  #pragma unroll
  for (int r = 0; r < 4; ++r) {
    int row = bb * 64 + ry * 4 + r;
    float* op = out + (size_t)row * NN + cc * 256;
    #pragma unroll
    for (int q = 0; q < 4; ++q) {
      float4 v = make_float4(acc[r][4*q+0], acc[r][4*q+1], acc[r][4*q+2], acc[r][4*q+3]);
      *(float4*)(op + q * 64 + cx * 4) = v;
    }
  }
}

extern "C" void kernel_launch(void* const* d_in, const int* in_sizes, int n_in,
                              void* d_out, int out_size, void* d_ws, size_t ws_size,
                              hipStream_t stream) {
  const float* x     = (const float*)d_in[0];   // (32,64,8192)
  const float* w1r   = (const float*)d_in[1];   // (64,64,32)
  const float* w1i   = (const float*)d_in[2];   // (64,64,32)
  const float* gw    = (const float*)d_in[3];   // (64,64)
  const float* gamma = (const float*)d_in[4];   // (32,)
  const float* beta  = (const float*)d_in[5];   // (32,)
  float* out = (float*)d_out;                   // (32,64,8192)
  float* ws = (float*)d_ws;
  // split-K partials live in d_out (16 MB of its 64 MB) — fully overwritten by k_inv later
  float* part = (float*)d_out;

  hipLaunchKernelGGL(k_trig,       dim3(2048), dim3(256), 0, stream, ws);
  hipLaunchKernelGGL(k_cft_tables, dim3(20),   dim3(256), 0, stream, ws);
  hipLaunchKernelGGL(k_transpose,  dim3(512),  dim3(256), 0, stream, w1r, w1i, gw, ws);
  hipLaunchKernelGGL(k_fwd_gemm,   dim3(1024), dim3(256), 0, stream, x, ws, part);
  hipLaunchKernelGGL(k_fred,       dim3(512),  dim3(256), 0, stream, part, ws);
  hipLaunchKernelGGL(k_cft,        dim3(512),  dim3(256), 0, stream, x, gamma, beta, ws);
  hipLaunchKernelGGL(k_gate,       dim3(1024), dim3(64),  0, stream, ws);
  hipLaunchKernelGGL(k_inv,        dim3(1024), dim3(256), 0, stream, ws, out);
}